// Round 8
// baseline (121610.535 us; speedup 1.0000x reference)
//
#include <hip/hip_runtime.h>
#include <stdint.h>

#define NTOK 256
#define NOUT 128
#define DIM 64
#define NB 128
#define CAP 1024
#define LCAP 512
#define PCAP 1024
#define NMERGE 128
#define KAPPA 0.24f
#define SCREEN 0.2395f
#define NTILES84 1056
#define TILES_PER_SUB84 528

__device__ __forceinline__ unsigned mono_f32(float s) {
  unsigned u = __float_as_uint(s);
  return (u & 0x80000000u) ? ~u : (u | 0x80000000u);
}

__device__ __forceinline__ unsigned long long shflx64(unsigned long long x, int m) {
  unsigned lo = (unsigned)x, hi = (unsigned)(x >> 32);
  lo = __shfl_xor(lo, m);
  hi = __shfl_xor(hi, m);
  return ((unsigned long long)hi << 32) | lo;
}

// invert T -> (ti, tj) on the 8x4 tile grid: ti in [0,32), tj in [2*ti, 64)
__device__ __forceinline__ void tile84(int T, int& tio, int& tjo) {
  float tf = (65.0f - sqrtf(4225.0f - 4.0f * (float)T)) * 0.5f;
  int t = (int)tf;
  if (t < 0) t = 0;
  if (t > 31) t = 31;
  while (t < 31 && 65 * (t + 1) - (t + 1) * (t + 1) <= T) ++t;
  while (t > 0 && 65 * t - t * t > T) --t;
  tio = t;
  tjo = 2 * t + (T - (65 * t - t * t));
}

// norm with EXACT same f64 accumulation grouping as gm_gram's normalize
__device__ __forceinline__ double knorm(const float* kp) {
  double s0 = 0.0, s1 = 0.0;
  for (int q = 0; q < 8; ++q) {
    const float* p = kp + q * 4;
    s0 += (double)p[0] * p[0] + (double)p[1] * p[1] +
          (double)p[2] * p[2] + (double)p[3] * p[3];
  }
  for (int q = 0; q < 8; ++q) {
    const float* p = kp + 32 + q * 4;
    s1 += (double)p[0] * p[0] + (double)p[1] * p[1] +
          (double)p[2] * p[2] + (double)p[3] * p[3];
  }
  return sqrt(s0 + s1);
}

#define CEX(a, b, up)                         \
  do {                                        \
    unsigned long long _a = (a), _b = (b);    \
    bool _sw = (up) ? (_a < _b) : (_a > _b);  \
    if (_sw) { (a) = _b; (b) = _a; }          \
  } while (0)

#define KEEP(v, o, km) ((km) ? ((v) > (o) ? (v) : (o)) : ((v) < (o) ? (v) : (o)))

// ============ kernel A: gram screen + exact f64 + fixed-segment flush ============
// grid 256 (2 WGs/batch), block 512. No global atomics, no memset needed.
// LDS: knT 64KB @0, lpairs 4KB @65536, lkeys 4KB @69632, lmisc @73728
#define SMEM_A 73760
__global__ __launch_bounds__(512) void gm_gram(const float* __restrict__ K,
                                               unsigned* __restrict__ gcnt,
                                               unsigned long long* __restrict__ gkeys) {
  extern __shared__ char smem[];
  float* knT = (float*)smem;
  unsigned* lpairs = (unsigned*)(smem + 65536);
  unsigned long long* lkeys = (unsigned long long*)(smem + 69632);
  int* lmisc = (int*)(smem + 73728);

  const int tid = threadIdx.x;
  const int b = blockIdx.x >> 1, sub = blockIdx.x & 1;

  if (tid == 0) { lmisc[0] = 0; lmisc[1] = 0; }

  // normalize -> knT[d][t] (bit-identical to prior rounds)
  {
    const int t = tid >> 1, h = tid & 1;
    const float* kp = K + ((size_t)b * NTOK + t) * DIM + h * 32;
    double ss = 0.0;
    float vals[32];
#pragma unroll
    for (int q = 0; q < 8; ++q) {
      float4 v4 = *reinterpret_cast<const float4*>(kp + q * 4);
      vals[q * 4 + 0] = v4.x; vals[q * 4 + 1] = v4.y;
      vals[q * 4 + 2] = v4.z; vals[q * 4 + 3] = v4.w;
      ss += (double)v4.x * v4.x + (double)v4.y * v4.y +
            (double)v4.z * v4.z + (double)v4.w * v4.w;
    }
    double other = __shfl_xor(ss, 1);
    double nrm = sqrt(ss + other);
#pragma unroll
    for (int q = 0; q < 32; ++q)
      knT[(h * 32 + q) * NTOK + t] = (float)((double)vals[q] / nrm);
  }
  __syncthreads();

  // f32 screen over this sub's 8x4 tiles (fmaf chain bit-identical to R7)
  const int base = sub * TILES_PER_SUB84;
  for (int t = tid; t < TILES_PER_SUB84; t += 512) {
    int ti, tj;
    tile84(base + t, ti, tj);
    const int i0 = ti * 8, j0 = tj * 4;

    float acc[8][4] = {};
#pragma unroll 4
    for (int d = 0; d < 64; ++d) {
      const float* row = knT + d * NTOK;
      const float4 a0 = *reinterpret_cast<const float4*>(row + i0);
      const float4 a1 = *reinterpret_cast<const float4*>(row + i0 + 4);
      const float4 bv = *reinterpret_cast<const float4*>(row + j0);
      const float aa[8] = {a0.x, a0.y, a0.z, a0.w, a1.x, a1.y, a1.z, a1.w};
      const float bb[4] = {bv.x, bv.y, bv.z, bv.w};
#pragma unroll
      for (int r = 0; r < 8; ++r)
#pragma unroll
        for (int c = 0; c < 4; ++c)
          acc[r][c] = fmaf(aa[r], bb[c], acc[r][c]);
    }
#pragma unroll
    for (int r = 0; r < 8; ++r)
#pragma unroll
      for (int c = 0; c < 4; ++c) {
        const int i = i0 + r, j = j0 + c;
        if (i < j && acc[r][c] >= SCREEN) {
          const int idx = atomicAdd(&lmisc[0], 1);
          if (idx < PCAP) lpairs[idx] = (unsigned)((i << 8) | j);
        }
      }
  }
  __syncthreads();

  // compact exact-f64 recompute
  const int npRaw = lmisc[0];
  const int np = npRaw > PCAP ? PCAP : npRaw;
  for (int e = tid; e < np; e += 512) {
    const unsigned p = lpairs[e];
    const int i = (int)(p >> 8), j = (int)(p & 255u);
    double s = 0.0;
    for (int d = 0; d < 64; ++d)
      s = fma((double)knT[d * NTOK + i], (double)knT[d * NTOK + j], s);
    const float sf = (float)s;
    if (sf >= KAPPA) {
      const unsigned long long key =
          ((unsigned long long)mono_f32(sf) << 16) |
          (unsigned)(65535 - ((i << 8) | j));
      const int idx = atomicAdd(&lmisc[1], 1);
      if (idx < LCAP) lkeys[idx] = key;
    }
  }
  __syncthreads();

  // fixed-segment flush; count written directly (no global atomics)
  const int nkRaw = lmisc[1];
  if (tid == 0)
    gcnt[2 * b + sub] = (npRaw > PCAP) ? 0x7FFFFFFFu : (unsigned)nkRaw;
  const int nk = nkRaw > LCAP ? LCAP : nkRaw;
  unsigned long long* seg = gkeys + (size_t)b * CAP + (size_t)sub * LCAP;
  for (int e = tid; e < nk; e += 512) seg[e] = lkeys[e];
}

// ============ kernel B: sort + serial-shfl walk + epilogue ============
// grid 128, block 512, static ~45KB LDS.
__global__ __launch_bounds__(512) void gm_walk(const float* __restrict__ K,
                                               const float* __restrict__ V,
                                               float* __restrict__ OUT,
                                               const unsigned* __restrict__ gcnt,
                                               const unsigned long long* __restrict__ gkeys) {
  __shared__ unsigned long long keys[CAP];   // 8KB
  __shared__ float accO[NOUT * DIM];         // 32KB
  __shared__ int gid[NTOK];
  __shared__ int cnt256[NTOK];
  __shared__ int scn[NTOK];
  __shared__ int rep[NOUT];
  __shared__ int misc[4];
  __shared__ unsigned long long red[8];
  __shared__ unsigned long long bkey[1];

  const int tid = threadIdx.x;
  const int lane = tid & 63;
  const int wid = tid >> 6;
  const int b = blockIdx.x;

  const unsigned n0 = gcnt[2 * b], n1 = gcnt[2 * b + 1];
  const bool fullFB = (n0 > LCAP) || (n1 > LCAP);
  const int n0c = n0 > LCAP ? LCAP : (int)n0;
  const int n1c = n1 > LCAP ? LCAP : (int)n1;
  const int cntC = n0c + n1c;

  if (tid == 0) misc[3] = fullFB ? 0 : NMERGE;
  if (tid < NTOK) gid[tid] = tid;

  // load both segments into LDS with zero padding
  {
    const unsigned long long* gk = gkeys + (size_t)b * CAP;
    for (int e = tid; e < CAP; e += 512) {
      const int seg = e >> 9, off = e & (LCAP - 1);
      const int lim = seg ? n1c : n0c;
      keys[e] = (off < lim) ? gk[e] : 0ULL;
    }
  }
  __syncthreads();

  // ---- bitonic sort (descending) of 1024 keys, 2 keys/thread ----
  {
    const int e0 = 2 * tid;
    unsigned long long v0 = keys[e0], v1 = keys[e0 + 1];

    for (int kk = 2; kk <= CAP; kk <<= 1) {
      for (int jj = kk >> 1; jj > 0; jj >>= 1) {
        if (jj >= 128) {
          __syncthreads();
          keys[e0] = v0; keys[e0 + 1] = v1;
          __syncthreads();
          const int p0 = e0 ^ jj;
          const unsigned long long o0 = keys[p0], o1 = keys[p0 + 1];
          const bool km = ((e0 & kk) == 0) == ((e0 & jj) == 0);
          v0 = KEEP(v0, o0, km); v1 = KEEP(v1, o1, km);
        } else if (jj >= 2) {
          const int m = jj >> 1;
          const unsigned long long o0 = shflx64(v0, m), o1 = shflx64(v1, m);
          const bool km = ((e0 & kk) == 0) == ((e0 & jj) == 0);
          v0 = KEEP(v0, o0, km); v1 = KEEP(v1, o1, km);
        } else {
          const bool up = ((e0 & kk) == 0);
          CEX(v0, v1, up);
        }
      }
    }
    __syncthreads();
    keys[e0] = v0; keys[e0 + 1] = v1;
  }
  __syncthreads();

  // ---- serial-shfl walk (wave 0), gid entirely in registers (R4-proven) ----
  if (!fullFB && wid == 0) {
    int rg0 = lane, rg1 = 64 + lane, rg2 = 128 + lane, rg3 = 192 + lane;
    int done = 0;
    for (int cursor = 0; cursor < cntC && done < NMERGE; cursor += 64) {
      const int idx = cursor + lane;
      const unsigned long long key = (idx < cntC) ? keys[idx] : 0ULL;
      const int pi = 255 - (int)((key >> 8) & 255);
      const int pj = 255 - (int)(key & 255);
      const int sli = pi & 63, ssi = pi >> 6;
      const int slj = pj & 63, ssj = pj >> 6;
      const int a0 = __shfl(rg0, sli), a1 = __shfl(rg1, sli),
                a2 = __shfl(rg2, sli), a3 = __shfl(rg3, sli);
      const int b0 = __shfl(rg0, slj), b1 = __shfl(rg1, slj),
                b2 = __shfl(rg2, slj), b3 = __shfl(rg3, slj);
      int gpi = (ssi == 0) ? a0 : (ssi == 1) ? a1 : (ssi == 2) ? a2 : a3;
      int gpj = (ssj == 0) ? b0 : (ssj == 1) ? b1 : (ssj == 2) ? b2 : b3;
      if (key == 0ULL) { gpi = 0; gpj = 0; }
      for (;;) {
        const unsigned long long mask = __ballot(gpi != gpj);
        if (!mask) break;
        const int f = __ffsll((long long)mask) - 1;
        const int gi = __shfl(gpi, f), gj = __shfl(gpj, f);
        if (lane == f) gpi = gpj;
        if (gpi == gi) gpi = gj;
        if (gpj == gi) gpj = gj;
        if (rg0 == gi) rg0 = gj;
        if (rg1 == gi) rg1 = gj;
        if (rg2 == gi) rg2 = gj;
        if (rg3 == gi) rg3 = gj;
        if (++done == NMERGE) break;
      }
    }
    gid[lane] = rg0; gid[64 + lane] = rg1;
    gid[128 + lane] = rg2; gid[192 + lane] = rg3;
    if (lane == 0) misc[3] = done;
  }
  __syncthreads();

  // ---- exact fallback (never taken in practice): K-based argmax per merge ----
  {
    const int start = misc[3];
    for (int mg = start; mg < NMERGE; ++mg) {
      unsigned long long best = 0ULL;
      const int p = tid >> 2, q = tid & 3;
      const int jA = 128 + p, jB = 127 - p;
      const int lenA = jA;
      const int s0 = q * 64, s1 = (q == 3) ? 255 : (q * 64 + 64);
      for (int e = s0; e < s1; ++e) {
        const int i = (e < lenA) ? e : (e - lenA);
        const int j = (e < lenA) ? jA : jB;
        if (gid[i] != gid[j]) {
          const float* ki = K + ((size_t)b * NTOK + i) * DIM;
          const float* kj = K + ((size_t)b * NTOK + j) * DIM;
          const double ni = knorm(ki), nj = knorm(kj);
          double s = 0.0;
          for (int d = 0; d < 64; ++d) {
            const float ai = (float)((double)ki[d] / ni);
            const float aj = (float)((double)kj[d] / nj);
            s = fma((double)ai, (double)aj, s);
          }
          const unsigned long long key =
              ((unsigned long long)mono_f32((float)s) << 16) |
              (unsigned)(65535 - ((i << 8) | j));
          if (key > best) best = key;
        }
      }
#pragma unroll
      for (int off = 32; off; off >>= 1) {
        unsigned long long o = __shfl_down(best, off);
        if (o > best) best = o;
      }
      if (lane == 0) red[wid] = best;
      __syncthreads();
      if (tid == 0) {
        unsigned long long mx = red[0];
        for (int w = 1; w < 8; ++w)
          if (red[w] > mx) mx = red[w];
        bkey[0] = mx;
      }
      __syncthreads();
      const unsigned long long bk = bkey[0];
      const int pi = 255 - (int)((bk >> 8) & 255);
      const int pj = 255 - (int)(bk & 255);
      const int gi = gid[pi], gj = gid[pj];
      __syncthreads();
      if (tid < NTOK && gid[tid] == gi) gid[tid] = gj;
      __syncthreads();
    }
  }
  __syncthreads();

  // ---- sizes + single-wave prefix scan + slots ----
  if (tid < NTOK) cnt256[tid] = 0;
  for (int e = tid; e < NOUT * DIM; e += 512) accO[e] = 0.0f;
  __syncthreads();
  if (tid < NTOK) atomicAdd(&cnt256[gid[tid]], 1);
  __syncthreads();
  if (wid == 0) {
    const int t4 = lane * 4;
    const int c0 = cnt256[t4 + 0] != 0, c1 = cnt256[t4 + 1] != 0,
              c2 = cnt256[t4 + 2] != 0, c3 = cnt256[t4 + 3] != 0;
    const int tot = c0 + c1 + c2 + c3;
    int run = tot;
#pragma unroll
    for (int off = 1; off < 64; off <<= 1) {
      int o = __shfl_up(run, off);
      if (lane >= off) run += o;
    }
    const int bs = run - tot;
    scn[t4 + 0] = bs + c0;
    scn[t4 + 1] = bs + c0 + c1;
    scn[t4 + 2] = bs + c0 + c1 + c2;
    scn[t4 + 3] = bs + tot;
  }
  __syncthreads();
  if (tid < NTOK && cnt256[tid]) rep[scn[tid] - 1] = tid;
  __syncthreads();

  // ---- accumulate V into slots ----
  {
    const int t = tid >> 1, h = tid & 1;
    const int slot = scn[gid[t]] - 1;
    const float* vp = V + ((size_t)b * NTOK + t) * DIM + h * 32;
    float* dst = accO + slot * DIM + h * 32;
#pragma unroll
    for (int q = 0; q < 8; ++q) {
      float4 v4 = *reinterpret_cast<const float4*>(vp + q * 4);
      atomicAdd(&dst[q * 4 + 0], v4.x);
      atomicAdd(&dst[q * 4 + 1], v4.y);
      atomicAdd(&dst[q * 4 + 2], v4.z);
      atomicAdd(&dst[q * 4 + 3], v4.w);
    }
  }
  __syncthreads();

  // ---- write outputs ----
  float* outMain = OUT + (size_t)b * (NOUT * DIM);
  for (int e = tid; e < NOUT * DIM; e += 512) {
    const int o = e >> 6;
    const float sz = (float)cnt256[rep[o]];
    outMain[e] = accO[e] / sz;
  }
  float* outSz = OUT + (size_t)NB * NOUT * DIM + (size_t)b * NOUT;
  for (int o = tid; o < NOUT; o += 512) outSz[o] = (float)cnt256[rep[o]];
}

// ============ fused fallback (R7, known-passing) — used only if ws too small ============
#define SMEM_F 83584
__global__ __launch_bounds__(512) void gm_fused(const float* __restrict__ K,
                                                const float* __restrict__ V,
                                                float* __restrict__ OUT) {
  extern __shared__ char smem[];
  float* knT = (float*)smem;
  float* accO = (float*)smem;
  unsigned long long* keys = (unsigned long long*)(smem + 65536);
  unsigned* lpairs = (unsigned*)(smem + 73728);
  int* gid = (int*)(smem + 77824);
  unsigned* claimA = (unsigned*)(smem + 78848);
  int* gmap = (int*)(smem + 79872);
  int* cnt256 = (int*)(smem + 80896);
  int* scn = (int*)(smem + 81920);
  int* rep = (int*)(smem + 82944);
  unsigned long long* red = (unsigned long long*)(smem + 83456);
  unsigned long long* bkey = (unsigned long long*)(smem + 83520);
  int* misc = (int*)(smem + 83528);

  const int tid = threadIdx.x;
  const int lane = tid & 63;
  const int wid = tid >> 6;
  const int b = blockIdx.x;

  if (tid == 0) { misc[0] = 0; misc[1] = 0; }
  if (tid < NTOK) {
    gid[tid] = tid;
    claimA[tid] = 0xFFFFFFFFu;
    gmap[tid] = -1;
  }

  {
    const int t = tid >> 1, h = tid & 1;
    const float* kp = K + ((size_t)b * NTOK + t) * DIM + h * 32;
    double ss = 0.0;
    float vals[32];
#pragma unroll
    for (int q = 0; q < 8; ++q) {
      float4 v4 = *reinterpret_cast<const float4*>(kp + q * 4);
      vals[q * 4 + 0] = v4.x; vals[q * 4 + 1] = v4.y;
      vals[q * 4 + 2] = v4.z; vals[q * 4 + 3] = v4.w;
      ss += (double)v4.x * v4.x + (double)v4.y * v4.y +
            (double)v4.z * v4.z + (double)v4.w * v4.w;
    }
    double other = __shfl_xor(ss, 1);
    double nrm = sqrt(ss + other);
#pragma unroll
    for (int q = 0; q < 32; ++q)
      knT[(h * 32 + q) * NTOK + t] = (float)((double)vals[q] / nrm);
  }
  __syncthreads();

  for (int t = tid; t < NTILES84; t += 512) {
    int ti, tj;
    tile84(t, ti, tj);
    const int i0 = ti * 8, j0 = tj * 4;
    float acc[8][4] = {};
#pragma unroll 4
    for (int d = 0; d < 64; ++d) {
      const float* row = knT + d * NTOK;
      const float4 a0 = *reinterpret_cast<const float4*>(row + i0);
      const float4 a1 = *reinterpret_cast<const float4*>(row + i0 + 4);
      const float4 bv = *reinterpret_cast<const float4*>(row + j0);
      const float aa[8] = {a0.x, a0.y, a0.z, a0.w, a1.x, a1.y, a1.z, a1.w};
      const float bb[4] = {bv.x, bv.y, bv.z, bv.w};
#pragma unroll
      for (int r = 0; r < 8; ++r)
#pragma unroll
        for (int c = 0; c < 4; ++c)
          acc[r][c] = fmaf(aa[r], bb[c], acc[r][c]);
    }
#pragma unroll
    for (int r = 0; r < 8; ++r)
#pragma unroll
      for (int c = 0; c < 4; ++c) {
        const int i = i0 + r, j = j0 + c;
        if (i < j && acc[r][c] >= SCREEN) {
          const int idx = atomicAdd(&misc[0], 1);
          if (idx < PCAP) lpairs[idx] = (unsigned)((i << 8) | j);
        }
      }
  }
  __syncthreads();

  const int npRaw = misc[0];
  const int np = npRaw > PCAP ? PCAP : npRaw;
  const bool fullFB = (npRaw > PCAP);
  for (int e = tid; e < np; e += 512) {
    const unsigned p = lpairs[e];
    const int i = (int)(p >> 8), j = (int)(p & 255u);
    double s = 0.0;
    for (int d = 0; d < 64; ++d)
      s = fma((double)knT[d * NTOK + i], (double)knT[d * NTOK + j], s);
    const float sf = (float)s;
    if (sf >= KAPPA) {
      const unsigned long long key =
          ((unsigned long long)mono_f32(sf) << 16) |
          (unsigned)(65535 - ((i << 8) | j));
      const int idx = atomicAdd(&misc[1], 1);
      keys[idx] = key;
    }
  }
  if (tid == 0) misc[3] = fullFB ? 0 : NMERGE;
  __syncthreads();
  const int nk = misc[1];

  {
    const int e0 = 2 * tid;
    unsigned long long v0 = (e0 + 0 < nk) ? keys[e0 + 0] : 0ULL;
    unsigned long long v1 = (e0 + 1 < nk) ? keys[e0 + 1] : 0ULL;
    for (int kk = 2; kk <= CAP; kk <<= 1) {
      for (int jj = kk >> 1; jj > 0; jj >>= 1) {
        if (jj >= 128) {
          __syncthreads();
          keys[e0] = v0; keys[e0 + 1] = v1;
          __syncthreads();
          const int p0 = e0 ^ jj;
          const unsigned long long o0 = keys[p0], o1 = keys[p0 + 1];
          const bool km = ((e0 & kk) == 0) == ((e0 & jj) == 0);
          v0 = KEEP(v0, o0, km); v1 = KEEP(v1, o1, km);
        } else if (jj >= 2) {
          const int m = jj >> 1;
          const unsigned long long o0 = shflx64(v0, m), o1 = shflx64(v1, m);
          const bool km = ((e0 & kk) == 0) == ((e0 & jj) == 0);
          v0 = KEEP(v0, o0, km); v1 = KEEP(v1, o1, km);
        } else {
          const bool up = ((e0 & kk) == 0);
          CEX(v0, v1, up);
        }
      }
    }
    __syncthreads();
    keys[e0] = v0; keys[e0 + 1] = v1;
  }
  __syncthreads();

  if (!fullFB && wid == 0) {
    int rg0 = lane, rg1 = 64 + lane, rg2 = 128 + lane, rg3 = 192 + lane;
    int done = 0;
    for (int cursor = 0; cursor < nk && done < NMERGE; cursor += 64) {
      const int idx = cursor + lane;
      const unsigned long long key = (idx < nk) ? keys[idx] : 0ULL;
      const int pi = 255 - (int)((key >> 8) & 255);
      const int pj = 255 - (int)(key & 255);
      const int sli = pi & 63, ssi = pi >> 6;
      const int slj = pj & 63, ssj = pj >> 6;
      const int a0 = __shfl(rg0, sli), a1 = __shfl(rg1, sli),
                a2 = __shfl(rg2, sli), a3 = __shfl(rg3, sli);
      const int b0 = __shfl(rg0, slj), b1 = __shfl(rg1, slj),
                b2 = __shfl(rg2, slj), b3 = __shfl(rg3, slj);
      int gpi = (ssi == 0) ? a0 : (ssi == 1) ? a1 : (ssi == 2) ? a2 : a3;
      int gpj = (ssj == 0) ? b0 : (ssj == 1) ? b1 : (ssj == 2) ? b2 : b3;
      if (key == 0ULL) { gpi = 0; gpj = 0; }
      for (;;) {
        const unsigned long long mask = __ballot(gpi != gpj);
        if (!mask) break;
        const int f = __ffsll((long long)mask) - 1;
        const int gi = __shfl(gpi, f), gj = __shfl(gpj, f);
        if (lane == f) gpi = gpj;
        if (gpi == gi) gpi = gj;
        if (gpj == gi) gpj = gj;
        if (rg0 == gi) rg0 = gj;
        if (rg1 == gi) rg1 = gj;
        if (rg2 == gi) rg2 = gj;
        if (rg3 == gi) rg3 = gj;
        if (++done == NMERGE) break;
      }
    }
    gid[lane] = rg0; gid[64 + lane] = rg1;
    gid[128 + lane] = rg2; gid[192 + lane] = rg3;
    if (lane == 0) misc[3] = done;
  }
  __syncthreads();

  {
    const int start = misc[3];
    for (int mg = start; mg < NMERGE; ++mg) {
      unsigned long long best = 0ULL;
      const int p = tid >> 2, q = tid & 3;
      const int jA = 128 + p, jB = 127 - p;
      const int lenA = jA;
      const int s0 = q * 64, s1 = (q == 3) ? 255 : (q * 64 + 64);
      for (int e = s0; e < s1; ++e) {
        const int i = (e < lenA) ? e : (e - lenA);
        const int j = (e < lenA) ? jA : jB;
        if (gid[i] != gid[j]) {
          double s = 0.0;
          for (int d = 0; d < 64; ++d)
            s = fma((double)knT[d * NTOK + i], (double)knT[d * NTOK + j], s);
          const unsigned long long key =
              ((unsigned long long)mono_f32((float)s) << 16) |
              (unsigned)(65535 - ((i << 8) | j));
          if (key > best) best = key;
        }
      }
#pragma unroll
      for (int off = 32; off; off >>= 1) {
        unsigned long long o = __shfl_down(best, off);
        if (o > best) best = o;
      }
      if (lane == 0) red[wid] = best;
      __syncthreads();
      if (tid == 0) {
        unsigned long long mx = red[0];
        for (int w = 1; w < 8; ++w)
          if (red[w] > mx) mx = red[w];
        bkey[0] = mx;
      }
      __syncthreads();
      const unsigned long long bk = bkey[0];
      const int pi = 255 - (int)((bk >> 8) & 255);
      const int pj = 255 - (int)(bk & 255);
      const int gi = gid[pi], gj = gid[pj];
      __syncthreads();
      if (tid < NTOK && gid[tid] == gi) gid[tid] = gj;
      __syncthreads();
    }
  }
  __syncthreads();

  if (tid < NTOK) cnt256[tid] = 0;
  for (int e = tid; e < NOUT * DIM; e += 512) accO[e] = 0.0f;
  __syncthreads();
  if (tid < NTOK) atomicAdd(&cnt256[gid[tid]], 1);
  __syncthreads();
  if (wid == 0) {
    const int t4 = lane * 4;
    const int c0 = cnt256[t4 + 0] != 0, c1 = cnt256[t4 + 1] != 0,
              c2 = cnt256[t4 + 2] != 0, c3 = cnt256[t4 + 3] != 0;
    const int tot = c0 + c1 + c2 + c3;
    int run = tot;
#pragma unroll
    for (int off = 1; off < 64; off <<= 1) {
      int o = __shfl_up(run, off);
      if (lane >= off) run += o;
    }
    const int bs = run - tot;
    scn[t4 + 0] = bs + c0;
    scn[t4 + 1] = bs + c0 + c1;
    scn[t4 + 2] = bs + c0 + c1 + c2;
    scn[t4 + 3] = bs + tot;
  }
  __syncthreads();
  if (tid < NTOK && cnt256[tid]) rep[scn[tid] - 1] = tid;
  __syncthreads();

  {
    const int t = tid >> 1, h = tid & 1;
    const int slot = scn[gid[t]] - 1;
    const float* vp = V + ((size_t)b * NTOK + t) * DIM + h * 32;
    float* dst = accO + slot * DIM + h * 32;
#pragma unroll
    for (int q = 0; q < 8; ++q) {
      float4 v4 = *reinterpret_cast<const float4*>(vp + q * 4);
      atomicAdd(&dst[q * 4 + 0], v4.x);
      atomicAdd(&dst[q * 4 + 1], v4.y);
      atomicAdd(&dst[q * 4 + 2], v4.z);
      atomicAdd(&dst[q * 4 + 3], v4.w);
    }
  }
  __syncthreads();

  float* outMain = OUT + (size_t)b * (NOUT * DIM);
  for (int e = tid; e < NOUT * DIM; e += 512) {
    const int o = e >> 6;
    const float sz = (float)cnt256[rep[o]];
    outMain[e] = accO[e] / sz;
  }
  float* outSz = OUT + (size_t)NB * NOUT * DIM + (size_t)b * NOUT;
  for (int o = tid; o < NOUT; o += 512) outSz[o] = (float)cnt256[rep[o]];
}

extern "C" void kernel_launch(void* const* d_in, const int* in_sizes, int n_in,
                              void* d_out, int out_size, void* d_ws, size_t ws_size,
                              hipStream_t stream) {
  const float* K = (const float*)d_in[0];
  const float* V = (const float*)d_in[1];
  float* OUT = (float*)d_out;
  (void)in_sizes; (void)n_in; (void)out_size;

  // ws: gcnt[256] u32 @0 (1KB), gkeys @1024 (1MB). No memset needed:
  // gm_gram writes every gcnt slot and every used gkeys slot each call.
  const size_t need = 1024 + (size_t)NB * CAP * sizeof(unsigned long long);
  if (ws_size >= need) {
    unsigned* gcnt = (unsigned*)d_ws;
    unsigned long long* gkeys = (unsigned long long*)((char*)d_ws + 1024);
    hipFuncSetAttribute(reinterpret_cast<const void*>(gm_gram),
                        hipFuncAttributeMaxDynamicSharedMemorySize, SMEM_A);
    gm_gram<<<dim3(NB * 2), dim3(512), SMEM_A, stream>>>(K, gcnt, gkeys);
    gm_walk<<<dim3(NB), dim3(512), 0, stream>>>(K, V, OUT, gcnt, gkeys);
  } else {
    hipFuncSetAttribute(reinterpret_cast<const void*>(gm_fused),
                        hipFuncAttributeMaxDynamicSharedMemorySize, SMEM_F);
    gm_fused<<<dim3(NB), dim3(512), SMEM_F, stream>>>(K, V, OUT);
  }
}

// Round 9
// 86.841 us; speedup vs baseline: 1400.3833x; 1400.3833x over previous
//
#include <hip/hip_runtime.h>
#include <stdint.h>

#define NTOK 256
#define NOUT 128
#define DIM 64
#define NB 128
#define LCAP 768          // keys per segment (expected ~447, 768 ≈ +15σ)
#define KTOT 1536         // stored keys per batch = 2*LCAP
#define SCAP 2048         // sort capacity (pow2 >= KTOT)
#define PCAP 1024
#define NMERGE 128
#define KAPPA 0.24f
#define SCREEN 0.2395f
#define NTILES84 1056
#define TILES_PER_SUB84 528

__device__ __forceinline__ unsigned mono_f32(float s) {
  unsigned u = __float_as_uint(s);
  return (u & 0x80000000u) ? ~u : (u | 0x80000000u);
}

__device__ __forceinline__ unsigned long long shflx64(unsigned long long x, int m) {
  unsigned lo = (unsigned)x, hi = (unsigned)(x >> 32);
  lo = __shfl_xor(lo, m);
  hi = __shfl_xor(hi, m);
  return ((unsigned long long)hi << 32) | lo;
}

// invert T -> (ti, tj) on the 8x4 tile grid: ti in [0,32), tj in [2*ti, 64)
__device__ __forceinline__ void tile84(int T, int& tio, int& tjo) {
  float tf = (65.0f - sqrtf(4225.0f - 4.0f * (float)T)) * 0.5f;
  int t = (int)tf;
  if (t < 0) t = 0;
  if (t > 31) t = 31;
  while (t < 31 && 65 * (t + 1) - (t + 1) * (t + 1) <= T) ++t;
  while (t > 0 && 65 * t - t * t > T) --t;
  tio = t;
  tjo = 2 * t + (T - (65 * t - t * t));
}

#define CEX(a, b, up)                         \
  do {                                        \
    unsigned long long _a = (a), _b = (b);    \
    bool _sw = (up) ? (_a < _b) : (_a > _b);  \
    if (_sw) { (a) = _b; (b) = _a; }          \
  } while (0)

#define KEEP(v, o, km) ((km) ? ((v) > (o) ? (v) : (o)) : ((v) < (o) ? (v) : (o)))

// ---- normalize K rows of batch b into knT[d][t], bit-identical everywhere ----
__device__ __forceinline__ void normalize_to_knT(const float* __restrict__ K,
                                                 float* __restrict__ knT,
                                                 int b, int tid) {
  const int t = tid >> 1, h = tid & 1;
  const float* kp = K + ((size_t)b * NTOK + t) * DIM + h * 32;
  double ss = 0.0;
  float vals[32];
#pragma unroll
  for (int q = 0; q < 8; ++q) {
    float4 v4 = *reinterpret_cast<const float4*>(kp + q * 4);
    vals[q * 4 + 0] = v4.x; vals[q * 4 + 1] = v4.y;
    vals[q * 4 + 2] = v4.z; vals[q * 4 + 3] = v4.w;
    ss += (double)v4.x * v4.x + (double)v4.y * v4.y +
          (double)v4.z * v4.z + (double)v4.w * v4.w;
  }
  double other = __shfl_xor(ss, 1);
  double nrm = sqrt(ss + other);
#pragma unroll
  for (int q = 0; q < 32; ++q)
    knT[(h * 32 + q) * NTOK + t] = (float)((double)vals[q] / nrm);
}

// ============ kernel A: gram screen + exact f64 + fixed-segment flush ============
// grid 256 (2 WGs/batch), block 512. No global atomics, no memset needed.
// LDS: knT 64KB @0, lpairs 4KB @65536, lkeys 6KB @69632, lmisc @75776
#define SMEM_A 75808
__global__ __launch_bounds__(512) void gm_gram(const float* __restrict__ K,
                                               unsigned* __restrict__ gcnt,
                                               unsigned long long* __restrict__ gkeys) {
  extern __shared__ char smem[];
  float* knT = (float*)smem;
  unsigned* lpairs = (unsigned*)(smem + 65536);
  unsigned long long* lkeys = (unsigned long long*)(smem + 69632);
  int* lmisc = (int*)(smem + 75776);

  const int tid = threadIdx.x;
  const int b = blockIdx.x >> 1, sub = blockIdx.x & 1;

  if (tid == 0) { lmisc[0] = 0; lmisc[1] = 0; }

  normalize_to_knT(K, knT, b, tid);
  __syncthreads();

  // f32 screen over this sub's 8x4 tiles (fmaf chain bit-identical to R6-R8)
  const int base = sub * TILES_PER_SUB84;
  for (int t = tid; t < TILES_PER_SUB84; t += 512) {
    int ti, tj;
    tile84(base + t, ti, tj);
    const int i0 = ti * 8, j0 = tj * 4;

    float acc[8][4] = {};
#pragma unroll 4
    for (int d = 0; d < 64; ++d) {
      const float* row = knT + d * NTOK;
      const float4 a0 = *reinterpret_cast<const float4*>(row + i0);
      const float4 a1 = *reinterpret_cast<const float4*>(row + i0 + 4);
      const float4 bv = *reinterpret_cast<const float4*>(row + j0);
      const float aa[8] = {a0.x, a0.y, a0.z, a0.w, a1.x, a1.y, a1.z, a1.w};
      const float bb[4] = {bv.x, bv.y, bv.z, bv.w};
#pragma unroll
      for (int r = 0; r < 8; ++r)
#pragma unroll
        for (int c = 0; c < 4; ++c)
          acc[r][c] = fmaf(aa[r], bb[c], acc[r][c]);
    }
#pragma unroll
    for (int r = 0; r < 8; ++r)
#pragma unroll
      for (int c = 0; c < 4; ++c) {
        const int i = i0 + r, j = j0 + c;
        if (i < j && acc[r][c] >= SCREEN) {
          const int idx = atomicAdd(&lmisc[0], 1);
          if (idx < PCAP) lpairs[idx] = (unsigned)((i << 8) | j);
        }
      }
  }
  __syncthreads();

  // compact exact-f64 recompute
  const int npRaw = lmisc[0];
  const int np = npRaw > PCAP ? PCAP : npRaw;
  for (int e = tid; e < np; e += 512) {
    const unsigned p = lpairs[e];
    const int i = (int)(p >> 8), j = (int)(p & 255u);
    double s = 0.0;
    for (int d = 0; d < 64; ++d)
      s = fma((double)knT[d * NTOK + i], (double)knT[d * NTOK + j], s);
    const float sf = (float)s;
    if (sf >= KAPPA) {
      const unsigned long long key =
          ((unsigned long long)mono_f32(sf) << 16) |
          (unsigned)(65535 - ((i << 8) | j));
      const int idx = atomicAdd(&lmisc[1], 1);
      if (idx < LCAP) lkeys[idx] = key;
    }
  }
  __syncthreads();

  // fixed-segment flush; count written directly (no global atomics)
  const int nkRaw = lmisc[1];
  if (tid == 0)
    gcnt[2 * b + sub] = (npRaw > PCAP) ? 0x7FFFFFFFu : (unsigned)nkRaw;
  const int nk = nkRaw > LCAP ? LCAP : nkRaw;
  unsigned long long* seg = gkeys + (size_t)b * KTOT + (size_t)sub * LCAP;
  for (int e = tid; e < nk; e += 512) seg[e] = lkeys[e];
}

// ============ kernel B: sort + serial-shfl walk + LDS fallback + epilogue ============
// grid 128, block 512, dynamic LDS.
// LDS: knT/accO alias 64KB @0, keys 16KB @65536, gid @81920, cnt256 @82944,
//      scn @83968, rep @84992, misc @85504, red @85520, bkey @85584
#define SMEM_W 85600
__global__ __launch_bounds__(512) void gm_walk(const float* __restrict__ K,
                                               const float* __restrict__ V,
                                               float* __restrict__ OUT,
                                               const unsigned* __restrict__ gcnt,
                                               const unsigned long long* __restrict__ gkeys) {
  extern __shared__ char smem[];
  float* knT = (float*)smem;          // live only during fallback
  float* accO = (float*)smem;         // live only during epilogue
  unsigned long long* keys = (unsigned long long*)(smem + 65536);
  int* gid = (int*)(smem + 81920);
  int* cnt256 = (int*)(smem + 82944);
  int* scn = (int*)(smem + 83968);
  int* rep = (int*)(smem + 84992);
  int* misc = (int*)(smem + 85504);
  unsigned long long* red = (unsigned long long*)(smem + 85520);
  unsigned long long* bkey = (unsigned long long*)(smem + 85584);

  const int tid = threadIdx.x;
  const int lane = tid & 63;
  const int wid = tid >> 6;
  const int b = blockIdx.x;

  const unsigned n0 = gcnt[2 * b], n1 = gcnt[2 * b + 1];
  const bool fullFB = (n0 > LCAP) || (n1 > LCAP);
  const int n0c = n0 > LCAP ? LCAP : (int)n0;
  const int n1c = n1 > LCAP ? LCAP : (int)n1;
  const int cntC = n0c + n1c;

  if (tid == 0) misc[3] = fullFB ? 0 : NMERGE;
  if (tid < NTOK) gid[tid] = tid;

  // load both segments into LDS with zero padding to SCAP
  {
    const unsigned long long* gk = gkeys + (size_t)b * KTOT;
    for (int e = tid; e < SCAP; e += 512) {
      unsigned long long v = 0ULL;
      if (e < KTOT) {
        const int seg = e / LCAP, off = e - seg * LCAP;
        const int lim = seg ? n1c : n0c;
        if (off < lim) v = gk[e];
      }
      keys[e] = v;
    }
  }
  __syncthreads();

  // ---- bitonic sort (descending) of 2048 slots, 4 keys/thread (R2-proven) ----
  {
    const int e0 = 4 * tid;
    unsigned long long v0 = keys[e0], v1 = keys[e0 + 1],
                       v2 = keys[e0 + 2], v3 = keys[e0 + 3];
    for (int kk = 2; kk <= SCAP; kk <<= 1) {
      for (int jj = kk >> 1; jj > 0; jj >>= 1) {
        if (jj >= 256) {
          __syncthreads();
          keys[e0] = v0; keys[e0 + 1] = v1; keys[e0 + 2] = v2; keys[e0 + 3] = v3;
          __syncthreads();
          const int p0 = e0 ^ jj;
          unsigned long long o0 = keys[p0], o1 = keys[p0 + 1],
                             o2 = keys[p0 + 2], o3 = keys[p0 + 3];
          const bool km = ((e0 & kk) == 0) == ((e0 & jj) == 0);
          v0 = KEEP(v0, o0, km); v1 = KEEP(v1, o1, km);
          v2 = KEEP(v2, o2, km); v3 = KEEP(v3, o3, km);
        } else if (jj >= 4) {
          const int m = jj >> 2;
          unsigned long long o0 = shflx64(v0, m), o1 = shflx64(v1, m),
                             o2 = shflx64(v2, m), o3 = shflx64(v3, m);
          const bool km = ((e0 & kk) == 0) == ((e0 & jj) == 0);
          v0 = KEEP(v0, o0, km); v1 = KEEP(v1, o1, km);
          v2 = KEEP(v2, o2, km); v3 = KEEP(v3, o3, km);
        } else if (jj == 2) {
          const bool up = ((e0 & kk) == 0);
          CEX(v0, v2, up); CEX(v1, v3, up);
        } else {
          bool up0, up1;
          if (kk == 2) { up0 = true; up1 = false; }
          else { up0 = up1 = ((e0 & kk) == 0); }
          CEX(v0, v1, up0); CEX(v2, v3, up1);
        }
      }
    }
    __syncthreads();
    keys[e0] = v0; keys[e0 + 1] = v1; keys[e0 + 2] = v2; keys[e0 + 3] = v3;
  }
  __syncthreads();

  // ---- serial-shfl walk (wave 0), gid entirely in registers (R4-proven) ----
  if (!fullFB && wid == 0) {
    int rg0 = lane, rg1 = 64 + lane, rg2 = 128 + lane, rg3 = 192 + lane;
    int done = 0;
    for (int cursor = 0; cursor < cntC && done < NMERGE; cursor += 64) {
      const int idx = cursor + lane;
      const unsigned long long key = (idx < cntC) ? keys[idx] : 0ULL;
      const int pi = 255 - (int)((key >> 8) & 255);
      const int pj = 255 - (int)(key & 255);
      const int sli = pi & 63, ssi = pi >> 6;
      const int slj = pj & 63, ssj = pj >> 6;
      const int a0 = __shfl(rg0, sli), a1 = __shfl(rg1, sli),
                a2 = __shfl(rg2, sli), a3 = __shfl(rg3, sli);
      const int b0 = __shfl(rg0, slj), b1 = __shfl(rg1, slj),
                b2 = __shfl(rg2, slj), b3 = __shfl(rg3, slj);
      int gpi = (ssi == 0) ? a0 : (ssi == 1) ? a1 : (ssi == 2) ? a2 : a3;
      int gpj = (ssj == 0) ? b0 : (ssj == 1) ? b1 : (ssj == 2) ? b2 : b3;
      if (key == 0ULL) { gpi = 0; gpj = 0; }
      for (;;) {
        const unsigned long long mask = __ballot(gpi != gpj);
        if (!mask) break;
        const int f = __ffsll((long long)mask) - 1;
        const int gi = __shfl(gpi, f), gj = __shfl(gpj, f);
        if (lane == f) gpi = gpj;
        if (gpi == gi) gpi = gj;
        if (gpj == gi) gpj = gj;
        if (rg0 == gi) rg0 = gj;
        if (rg1 == gi) rg1 = gj;
        if (rg2 == gi) rg2 = gj;
        if (rg3 == gi) rg3 = gj;
        if (++done == NMERGE) break;
      }
    }
    gid[lane] = rg0; gid[64 + lane] = rg1;
    gid[128 + lane] = rg2; gid[192 + lane] = rg3;
    if (lane == 0) misc[3] = done;
  }
  __syncthreads();

  // ---- exact fallback, now CHEAP: rebuild knT in LDS, argmax from LDS ----
  {
    const int start = misc[3];
    if (start < NMERGE) {
      normalize_to_knT(K, knT, b, tid);  // bit-identical to gm_gram's knT
      __syncthreads();
      for (int mg = start; mg < NMERGE; ++mg) {
        unsigned long long best = 0ULL;
        const int p = tid >> 2, q = tid & 3;
        const int jA = 128 + p, jB = 127 - p;
        const int lenA = jA;
        const int s0 = q * 64, s1 = (q == 3) ? 255 : (q * 64 + 64);
        for (int e = s0; e < s1; ++e) {
          const int i = (e < lenA) ? e : (e - lenA);
          const int j = (e < lenA) ? jA : jB;
          if (gid[i] != gid[j]) {
            double s = 0.0;
            for (int d = 0; d < 64; ++d)
              s = fma((double)knT[d * NTOK + i], (double)knT[d * NTOK + j], s);
            const unsigned long long key =
                ((unsigned long long)mono_f32((float)s) << 16) |
                (unsigned)(65535 - ((i << 8) | j));
            if (key > best) best = key;
          }
        }
#pragma unroll
        for (int off = 32; off; off >>= 1) {
          unsigned long long o = __shfl_down(best, off);
          if (o > best) best = o;
        }
        if (lane == 0) red[wid] = best;
        __syncthreads();
        if (tid == 0) {
          unsigned long long mx = red[0];
          for (int w = 1; w < 8; ++w)
            if (red[w] > mx) mx = red[w];
          bkey[0] = mx;
        }
        __syncthreads();
        const unsigned long long bk = bkey[0];
        const int pi = 255 - (int)((bk >> 8) & 255);
        const int pj = 255 - (int)(bk & 255);
        const int gi = gid[pi], gj = gid[pj];
        __syncthreads();
        if (tid < NTOK && gid[tid] == gi) gid[tid] = gj;
        __syncthreads();
      }
    }
  }
  __syncthreads();
  // knT dead from here; accO (alias) becomes live.

  // ---- sizes + single-wave prefix scan + slots ----
  if (tid < NTOK) cnt256[tid] = 0;
  for (int e = tid; e < NOUT * DIM; e += 512) accO[e] = 0.0f;
  __syncthreads();
  if (tid < NTOK) atomicAdd(&cnt256[gid[tid]], 1);
  __syncthreads();
  if (wid == 0) {
    const int t4 = lane * 4;
    const int c0 = cnt256[t4 + 0] != 0, c1 = cnt256[t4 + 1] != 0,
              c2 = cnt256[t4 + 2] != 0, c3 = cnt256[t4 + 3] != 0;
    const int tot = c0 + c1 + c2 + c3;
    int run = tot;
#pragma unroll
    for (int off = 1; off < 64; off <<= 1) {
      int o = __shfl_up(run, off);
      if (lane >= off) run += o;
    }
    const int bs = run - tot;
    scn[t4 + 0] = bs + c0;
    scn[t4 + 1] = bs + c0 + c1;
    scn[t4 + 2] = bs + c0 + c1 + c2;
    scn[t4 + 3] = bs + tot;
  }
  __syncthreads();
  if (tid < NTOK && cnt256[tid]) rep[scn[tid] - 1] = tid;
  __syncthreads();

  // ---- accumulate V into slots ----
  {
    const int t = tid >> 1, h = tid & 1;
    const int slot = scn[gid[t]] - 1;
    const float* vp = V + ((size_t)b * NTOK + t) * DIM + h * 32;
    float* dst = accO + slot * DIM + h * 32;
#pragma unroll
    for (int q = 0; q < 8; ++q) {
      float4 v4 = *reinterpret_cast<const float4*>(vp + q * 4);
      atomicAdd(&dst[q * 4 + 0], v4.x);
      atomicAdd(&dst[q * 4 + 1], v4.y);
      atomicAdd(&dst[q * 4 + 2], v4.z);
      atomicAdd(&dst[q * 4 + 3], v4.w);
    }
  }
  __syncthreads();

  // ---- write outputs ----
  float* outMain = OUT + (size_t)b * (NOUT * DIM);
  for (int e = tid; e < NOUT * DIM; e += 512) {
    const int o = e >> 6;
    const float sz = (float)cnt256[rep[o]];
    outMain[e] = accO[e] / sz;
  }
  float* outSz = OUT + (size_t)NB * NOUT * DIM + (size_t)b * NOUT;
  for (int o = tid; o < NOUT; o += 512) outSz[o] = (float)cnt256[rep[o]];
}

// ============ fused fallback (R7, known-passing) — used only if ws too small ============
#define FCAP 1024
#define SMEM_F 83584
__global__ __launch_bounds__(512) void gm_fused(const float* __restrict__ K,
                                                const float* __restrict__ V,
                                                float* __restrict__ OUT) {
  extern __shared__ char smem[];
  float* knT = (float*)smem;
  float* accO = (float*)smem;
  unsigned long long* keys = (unsigned long long*)(smem + 65536);
  unsigned* lpairs = (unsigned*)(smem + 73728);
  int* gid = (int*)(smem + 77824);
  int* cnt256 = (int*)(smem + 80896);
  int* scn = (int*)(smem + 81920);
  int* rep = (int*)(smem + 82944);
  unsigned long long* red = (unsigned long long*)(smem + 83456);
  unsigned long long* bkey = (unsigned long long*)(smem + 83520);
  int* misc = (int*)(smem + 83528);

  const int tid = threadIdx.x;
  const int lane = tid & 63;
  const int wid = tid >> 6;
  const int b = blockIdx.x;

  if (tid == 0) { misc[0] = 0; misc[1] = 0; }
  if (tid < NTOK) gid[tid] = tid;

  normalize_to_knT(K, knT, b, tid);
  __syncthreads();

  for (int t = tid; t < NTILES84; t += 512) {
    int ti, tj;
    tile84(t, ti, tj);
    const int i0 = ti * 8, j0 = tj * 4;
    float acc[8][4] = {};
#pragma unroll 4
    for (int d = 0; d < 64; ++d) {
      const float* row = knT + d * NTOK;
      const float4 a0 = *reinterpret_cast<const float4*>(row + i0);
      const float4 a1 = *reinterpret_cast<const float4*>(row + i0 + 4);
      const float4 bv = *reinterpret_cast<const float4*>(row + j0);
      const float aa[8] = {a0.x, a0.y, a0.z, a0.w, a1.x, a1.y, a1.z, a1.w};
      const float bb[4] = {bv.x, bv.y, bv.z, bv.w};
#pragma unroll
      for (int r = 0; r < 8; ++r)
#pragma unroll
        for (int c = 0; c < 4; ++c)
          acc[r][c] = fmaf(aa[r], bb[c], acc[r][c]);
    }
#pragma unroll
    for (int r = 0; r < 8; ++r)
#pragma unroll
      for (int c = 0; c < 4; ++c) {
        const int i = i0 + r, j = j0 + c;
        if (i < j && acc[r][c] >= SCREEN) {
          const int idx = atomicAdd(&misc[0], 1);
          if (idx < PCAP) lpairs[idx] = (unsigned)((i << 8) | j);
        }
      }
  }
  __syncthreads();

  const int npRaw = misc[0];
  const int np = npRaw > PCAP ? PCAP : npRaw;
  const bool fullFB = (npRaw > PCAP);
  for (int e = tid; e < np; e += 512) {
    const unsigned p = lpairs[e];
    const int i = (int)(p >> 8), j = (int)(p & 255u);
    double s = 0.0;
    for (int d = 0; d < 64; ++d)
      s = fma((double)knT[d * NTOK + i], (double)knT[d * NTOK + j], s);
    const float sf = (float)s;
    if (sf >= KAPPA) {
      const unsigned long long key =
          ((unsigned long long)mono_f32(sf) << 16) |
          (unsigned)(65535 - ((i << 8) | j));
      const int idx = atomicAdd(&misc[1], 1);
      keys[idx] = key;
    }
  }
  if (tid == 0) misc[3] = fullFB ? 0 : NMERGE;
  __syncthreads();
  const int nk = misc[1];

  {
    const int e0 = 2 * tid;
    unsigned long long v0 = (e0 + 0 < nk) ? keys[e0 + 0] : 0ULL;
    unsigned long long v1 = (e0 + 1 < nk) ? keys[e0 + 1] : 0ULL;
    for (int kk = 2; kk <= FCAP; kk <<= 1) {
      for (int jj = kk >> 1; jj > 0; jj >>= 1) {
        if (jj >= 128) {
          __syncthreads();
          keys[e0] = v0; keys[e0 + 1] = v1;
          __syncthreads();
          const int p0 = e0 ^ jj;
          const unsigned long long o0 = keys[p0], o1 = keys[p0 + 1];
          const bool km = ((e0 & kk) == 0) == ((e0 & jj) == 0);
          v0 = KEEP(v0, o0, km); v1 = KEEP(v1, o1, km);
        } else if (jj >= 2) {
          const int m = jj >> 1;
          const unsigned long long o0 = shflx64(v0, m), o1 = shflx64(v1, m);
          const bool km = ((e0 & kk) == 0) == ((e0 & jj) == 0);
          v0 = KEEP(v0, o0, km); v1 = KEEP(v1, o1, km);
        } else {
          const bool up = ((e0 & kk) == 0);
          CEX(v0, v1, up);
        }
      }
    }
    __syncthreads();
    keys[e0] = v0; keys[e0 + 1] = v1;
  }
  __syncthreads();

  if (!fullFB && wid == 0) {
    int rg0 = lane, rg1 = 64 + lane, rg2 = 128 + lane, rg3 = 192 + lane;
    int done = 0;
    for (int cursor = 0; cursor < nk && done < NMERGE; cursor += 64) {
      const int idx = cursor + lane;
      const unsigned long long key = (idx < nk) ? keys[idx] : 0ULL;
      const int pi = 255 - (int)((key >> 8) & 255);
      const int pj = 255 - (int)(key & 255);
      const int sli = pi & 63, ssi = pi >> 6;
      const int slj = pj & 63, ssj = pj >> 6;
      const int a0 = __shfl(rg0, sli), a1 = __shfl(rg1, sli),
                a2 = __shfl(rg2, sli), a3 = __shfl(rg3, sli);
      const int b0 = __shfl(rg0, slj), b1 = __shfl(rg1, slj),
                b2 = __shfl(rg2, slj), b3 = __shfl(rg3, slj);
      int gpi = (ssi == 0) ? a0 : (ssi == 1) ? a1 : (ssi == 2) ? a2 : a3;
      int gpj = (ssj == 0) ? b0 : (ssj == 1) ? b1 : (ssj == 2) ? b2 : b3;
      if (key == 0ULL) { gpi = 0; gpj = 0; }
      for (;;) {
        const unsigned long long mask = __ballot(gpi != gpj);
        if (!mask) break;
        const int f = __ffsll((long long)mask) - 1;
        const int gi = __shfl(gpi, f), gj = __shfl(gpj, f);
        if (lane == f) gpi = gpj;
        if (gpi == gi) gpi = gj;
        if (gpj == gi) gpj = gj;
        if (rg0 == gi) rg0 = gj;
        if (rg1 == gi) rg1 = gj;
        if (rg2 == gi) rg2 = gj;
        if (rg3 == gi) rg3 = gj;
        if (++done == NMERGE) break;
      }
    }
    gid[lane] = rg0; gid[64 + lane] = rg1;
    gid[128 + lane] = rg2; gid[192 + lane] = rg3;
    if (lane == 0) misc[3] = done;
  }
  __syncthreads();

  {
    const int start = misc[3];
    for (int mg = start; mg < NMERGE; ++mg) {
      unsigned long long best = 0ULL;
      const int p = tid >> 2, q = tid & 3;
      const int jA = 128 + p, jB = 127 - p;
      const int lenA = jA;
      const int s0 = q * 64, s1 = (q == 3) ? 255 : (q * 64 + 64);
      for (int e = s0; e < s1; ++e) {
        const int i = (e < lenA) ? e : (e - lenA);
        const int j = (e < lenA) ? jA : jB;
        if (gid[i] != gid[j]) {
          double s = 0.0;
          for (int d = 0; d < 64; ++d)
            s = fma((double)knT[d * NTOK + i], (double)knT[d * NTOK + j], s);
          const unsigned long long key =
              ((unsigned long long)mono_f32((float)s) << 16) |
              (unsigned)(65535 - ((i << 8) | j));
          if (key > best) best = key;
        }
      }
#pragma unroll
      for (int off = 32; off; off >>= 1) {
        unsigned long long o = __shfl_down(best, off);
        if (o > best) best = o;
      }
      if (lane == 0) red[wid] = best;
      __syncthreads();
      if (tid == 0) {
        unsigned long long mx = red[0];
        for (int w = 1; w < 8; ++w)
          if (red[w] > mx) mx = red[w];
        bkey[0] = mx;
      }
      __syncthreads();
      const unsigned long long bk = bkey[0];
      const int pi = 255 - (int)((bk >> 8) & 255);
      const int pj = 255 - (int)(bk & 255);
      const int gi = gid[pi], gj = gid[pj];
      __syncthreads();
      if (tid < NTOK && gid[tid] == gi) gid[tid] = gj;
      __syncthreads();
    }
  }
  __syncthreads();

  if (tid < NTOK) cnt256[tid] = 0;
  for (int e = tid; e < NOUT * DIM; e += 512) accO[e] = 0.0f;
  __syncthreads();
  if (tid < NTOK) atomicAdd(&cnt256[gid[tid]], 1);
  __syncthreads();
  if (wid == 0) {
    const int t4 = lane * 4;
    const int c0 = cnt256[t4 + 0] != 0, c1 = cnt256[t4 + 1] != 0,
              c2 = cnt256[t4 + 2] != 0, c3 = cnt256[t4 + 3] != 0;
    const int tot = c0 + c1 + c2 + c3;
    int run = tot;
#pragma unroll
    for (int off = 1; off < 64; off <<= 1) {
      int o = __shfl_up(run, off);
      if (lane >= off) run += o;
    }
    const int bs = run - tot;
    scn[t4 + 0] = bs + c0;
    scn[t4 + 1] = bs + c0 + c1;
    scn[t4 + 2] = bs + c0 + c1 + c2;
    scn[t4 + 3] = bs + tot;
  }
  __syncthreads();
  if (tid < NTOK && cnt256[tid]) rep[scn[tid] - 1] = tid;
  __syncthreads();

  {
    const int t = tid >> 1, h = tid & 1;
    const int slot = scn[gid[t]] - 1;
    const float* vp = V + ((size_t)b * NTOK + t) * DIM + h * 32;
    float* dst = accO + slot * DIM + h * 32;
#pragma unroll
    for (int q = 0; q < 8; ++q) {
      float4 v4 = *reinterpret_cast<const float4*>(vp + q * 4);
      atomicAdd(&dst[q * 4 + 0], v4.x);
      atomicAdd(&dst[q * 4 + 1], v4.y);
      atomicAdd(&dst[q * 4 + 2], v4.z);
      atomicAdd(&dst[q * 4 + 3], v4.w);
    }
  }
  __syncthreads();

  float* outMain = OUT + (size_t)b * (NOUT * DIM);
  for (int e = tid; e < NOUT * DIM; e += 512) {
    const int o = e >> 6;
    const float sz = (float)cnt256[rep[o]];
    outMain[e] = accO[e] / sz;
  }
  float* outSz = OUT + (size_t)NB * NOUT * DIM + (size_t)b * NOUT;
  for (int o = tid; o < NOUT; o += 512) outSz[o] = (float)cnt256[rep[o]];
}

extern "C" void kernel_launch(void* const* d_in, const int* in_sizes, int n_in,
                              void* d_out, int out_size, void* d_ws, size_t ws_size,
                              hipStream_t stream) {
  const float* K = (const float*)d_in[0];
  const float* V = (const float*)d_in[1];
  float* OUT = (float*)d_out;
  (void)in_sizes; (void)n_in; (void)out_size;

  // ws: gcnt[256] u32 @0 (1KB), gkeys @1024 (128*1536*8 = 1.5MB).
  // No memset needed: gm_gram writes every gcnt slot each call.
  const size_t need = 1024 + (size_t)NB * KTOT * sizeof(unsigned long long);
  if (ws_size >= need) {
    unsigned* gcnt = (unsigned*)d_ws;
    unsigned long long* gkeys = (unsigned long long*)((char*)d_ws + 1024);
    hipFuncSetAttribute(reinterpret_cast<const void*>(gm_gram),
                        hipFuncAttributeMaxDynamicSharedMemorySize, SMEM_A);
    hipFuncSetAttribute(reinterpret_cast<const void*>(gm_walk),
                        hipFuncAttributeMaxDynamicSharedMemorySize, SMEM_W);
    gm_gram<<<dim3(NB * 2), dim3(512), SMEM_A, stream>>>(K, gcnt, gkeys);
    gm_walk<<<dim3(NB), dim3(512), SMEM_W, stream>>>(K, V, OUT, gcnt, gkeys);
  } else {
    hipFuncSetAttribute(reinterpret_cast<const void*>(gm_fused),
                        hipFuncAttributeMaxDynamicSharedMemorySize, SMEM_F);
    gm_fused<<<dim3(NB), dim3(512), SMEM_F, stream>>>(K, V, OUT);
  }
}

// Round 10
// 85.499 us; speedup vs baseline: 1422.3617x; 1.0157x over previous
//
#include <hip/hip_runtime.h>
#include <stdint.h>

#define NTOK 256
#define NOUT 128
#define DIM 64
#define NB 128
#define LCAP 384          // keys per segment (expected ~224, +10.6 sigma)
#define NSEG 4
#define KTOT 1536         // NSEG * LCAP
#define WCAP 1024         // fast-path sort capacity (empirically >= all batches)
#define PCAPA 512         // screened pairs per gram sub-block
#define NMERGE 128
#define KAPPA 0.24f
#define SCREEN 0.2395f
#define NTILES84 1056
#define TILES_PER_SUB84 264

__device__ __forceinline__ unsigned mono_f32(float s) {
  unsigned u = __float_as_uint(s);
  return (u & 0x80000000u) ? ~u : (u | 0x80000000u);
}

__device__ __forceinline__ unsigned long long shflx64(unsigned long long x, int m) {
  unsigned lo = (unsigned)x, hi = (unsigned)(x >> 32);
  lo = __shfl_xor(lo, m);
  hi = __shfl_xor(hi, m);
  return ((unsigned long long)hi << 32) | lo;
}

// invert T -> (ti, tj) on the 8x4 tile grid: ti in [0,32), tj in [2*ti, 64)
__device__ __forceinline__ void tile84(int T, int& tio, int& tjo) {
  float tf = (65.0f - sqrtf(4225.0f - 4.0f * (float)T)) * 0.5f;
  int t = (int)tf;
  if (t < 0) t = 0;
  if (t > 31) t = 31;
  while (t < 31 && 65 * (t + 1) - (t + 1) * (t + 1) <= T) ++t;
  while (t > 0 && 65 * t - t * t > T) --t;
  tio = t;
  tjo = 2 * t + (T - (65 * t - t * t));
}

#define CEX(a, b, up)                         \
  do {                                        \
    unsigned long long _a = (a), _b = (b);    \
    bool _sw = (up) ? (_a < _b) : (_a > _b);  \
    if (_sw) { (a) = _b; (b) = _a; }          \
  } while (0)

#define KEEP(v, o, km) ((km) ? ((v) > (o) ? (v) : (o)) : ((v) < (o) ? (v) : (o)))

// ---- 256-thread normalize: thread t handles token t. f64 grouping is
// bit-identical to the original 2-thread version (s0/s1 per-half sums in
// ascending-q order; sqrt(s0+s1); IEEE add is commutative). ----
__device__ __forceinline__ void norm_tok(const float* __restrict__ K,
                                         float* __restrict__ knT,
                                         int b, int t) {
  const float* kp = K + ((size_t)b * NTOK + t) * DIM;
  float vals[64];
  double s0 = 0.0, s1 = 0.0;
#pragma unroll
  for (int q = 0; q < 8; ++q) {
    float4 v4 = *reinterpret_cast<const float4*>(kp + q * 4);
    vals[q * 4 + 0] = v4.x; vals[q * 4 + 1] = v4.y;
    vals[q * 4 + 2] = v4.z; vals[q * 4 + 3] = v4.w;
    s0 += (double)v4.x * v4.x + (double)v4.y * v4.y +
          (double)v4.z * v4.z + (double)v4.w * v4.w;
  }
#pragma unroll
  for (int q = 8; q < 16; ++q) {
    float4 v4 = *reinterpret_cast<const float4*>(kp + q * 4);
    vals[q * 4 + 0] = v4.x; vals[q * 4 + 1] = v4.y;
    vals[q * 4 + 2] = v4.z; vals[q * 4 + 3] = v4.w;
    s1 += (double)v4.x * v4.x + (double)v4.y * v4.y +
          (double)v4.z * v4.z + (double)v4.w * v4.w;
  }
  const double nrm = sqrt(s0 + s1);
#pragma unroll
  for (int d = 0; d < 64; ++d)
    knT[d * NTOK + t] = (float)((double)vals[d] / nrm);
}

// ---- 512-thread normalize (used by gm_fused fallback only) ----
__device__ __forceinline__ void normalize_to_knT(const float* __restrict__ K,
                                                 float* __restrict__ knT,
                                                 int b, int tid) {
  const int t = tid >> 1, h = tid & 1;
  const float* kp = K + ((size_t)b * NTOK + t) * DIM + h * 32;
  double ss = 0.0;
  float vals[32];
#pragma unroll
  for (int q = 0; q < 8; ++q) {
    float4 v4 = *reinterpret_cast<const float4*>(kp + q * 4);
    vals[q * 4 + 0] = v4.x; vals[q * 4 + 1] = v4.y;
    vals[q * 4 + 2] = v4.z; vals[q * 4 + 3] = v4.w;
    ss += (double)v4.x * v4.x + (double)v4.y * v4.y +
          (double)v4.z * v4.z + (double)v4.w * v4.w;
  }
  double other = __shfl_xor(ss, 1);
  double nrm = sqrt(ss + other);
#pragma unroll
  for (int q = 0; q < 32; ++q)
    knT[(h * 32 + q) * NTOK + t] = (float)((double)vals[q] / nrm);
}

// ============ kernel A: gram screen + exact f64 + fixed-segment flush ============
// grid 512 (4 WGs/batch), block 256. 2 blocks/CU. No global atomics, no memset.
// LDS: knT 64KB @0, lpairs 2KB @65536, lkeys 3KB @67584, lmisc @70656
#define SMEM_A 70672
__global__ __launch_bounds__(256) void gm_gram(const float* __restrict__ K,
                                               unsigned* __restrict__ gcnt,
                                               unsigned long long* __restrict__ gkeys) {
  extern __shared__ char smem[];
  float* knT = (float*)smem;
  unsigned* lpairs = (unsigned*)(smem + 65536);
  unsigned long long* lkeys = (unsigned long long*)(smem + 67584);
  int* lmisc = (int*)(smem + 70656);

  const int tid = threadIdx.x;
  const int b = blockIdx.x >> 2, sub = blockIdx.x & 3;

  if (tid == 0) { lmisc[0] = 0; lmisc[1] = 0; }
  norm_tok(K, knT, b, tid);
  __syncthreads();

  // f32 screen over this sub's 8x4 tiles (fmaf chain bit-identical to R6-R9)
  const int base = sub * TILES_PER_SUB84;
  for (int t = tid; t < TILES_PER_SUB84; t += 256) {
    int ti, tj;
    tile84(base + t, ti, tj);
    const int i0 = ti * 8, j0 = tj * 4;

    float acc[8][4] = {};
#pragma unroll 4
    for (int d = 0; d < 64; ++d) {
      const float* row = knT + d * NTOK;
      const float4 a0 = *reinterpret_cast<const float4*>(row + i0);
      const float4 a1 = *reinterpret_cast<const float4*>(row + i0 + 4);
      const float4 bv = *reinterpret_cast<const float4*>(row + j0);
      const float aa[8] = {a0.x, a0.y, a0.z, a0.w, a1.x, a1.y, a1.z, a1.w};
      const float bb[4] = {bv.x, bv.y, bv.z, bv.w};
#pragma unroll
      for (int r = 0; r < 8; ++r)
#pragma unroll
        for (int c = 0; c < 4; ++c)
          acc[r][c] = fmaf(aa[r], bb[c], acc[r][c]);
    }
#pragma unroll
    for (int r = 0; r < 8; ++r)
#pragma unroll
      for (int c = 0; c < 4; ++c) {
        const int i = i0 + r, j = j0 + c;
        if (i < j && acc[r][c] >= SCREEN) {
          const int idx = atomicAdd(&lmisc[0], 1);
          if (idx < PCAPA) lpairs[idx] = (unsigned)((i << 8) | j);
        }
      }
  }
  __syncthreads();

  // compact exact-f64 recompute (bit-identical chain to all prior rounds)
  const int npRaw = lmisc[0];
  const int np = npRaw > PCAPA ? PCAPA : npRaw;
  for (int e = tid; e < np; e += 256) {
    const unsigned p = lpairs[e];
    const int i = (int)(p >> 8), j = (int)(p & 255u);
    double s = 0.0;
    for (int d = 0; d < 64; ++d)
      s = fma((double)knT[d * NTOK + i], (double)knT[d * NTOK + j], s);
    const float sf = (float)s;
    if (sf >= KAPPA) {
      const unsigned long long key =
          ((unsigned long long)mono_f32(sf) << 16) |
          (unsigned)(65535 - ((i << 8) | j));
      const int idx = atomicAdd(&lmisc[1], 1);
      if (idx < LCAP) lkeys[idx] = key;
    }
  }
  __syncthreads();

  // fixed-segment flush; count written directly (no global atomics)
  const int nkRaw = lmisc[1];
  if (tid == 0)
    gcnt[NSEG * b + sub] =
        (npRaw > PCAPA || nkRaw > LCAP) ? 0x7FFFFFFFu : (unsigned)nkRaw;
  const int nk = nkRaw > LCAP ? LCAP : nkRaw;
  unsigned long long* seg = gkeys + (size_t)b * KTOT + (size_t)sub * LCAP;
  for (int e = tid; e < nk; e += 256) seg[e] = lkeys[e];
}

// ============ kernel B: packed load + 1024 sort + serial-shfl walk + epilogue ============
// grid 128, block 256, dynamic LDS ~76KB.
// LDS: knT/accO alias 64KB @0, keys 8KB @65536, gid @73728, cnt256 @74752,
//      scn @75776, rep @76800, misc @77312, red @77328, bkey @77360
#define SMEM_W 77376
__global__ __launch_bounds__(256) void gm_walk(const float* __restrict__ K,
                                               const float* __restrict__ V,
                                               float* __restrict__ OUT,
                                               const unsigned* __restrict__ gcnt,
                                               const unsigned long long* __restrict__ gkeys) {
  extern __shared__ char smem[];
  float* knT = (float*)smem;          // live only during fallback
  float* accO = (float*)smem;         // live only during epilogue
  unsigned long long* keys = (unsigned long long*)(smem + 65536);
  int* gid = (int*)(smem + 73728);
  int* cnt256 = (int*)(smem + 74752);
  int* scn = (int*)(smem + 75776);
  int* rep = (int*)(smem + 76800);
  int* misc = (int*)(smem + 77312);
  unsigned long long* red = (unsigned long long*)(smem + 77328);
  unsigned long long* bkey = (unsigned long long*)(smem + 77360);

  const int tid = threadIdx.x;
  const int lane = tid & 63;
  const int wid = tid >> 6;
  const int b = blockIdx.x;

  const unsigned m0 = gcnt[NSEG * b + 0], m1 = gcnt[NSEG * b + 1],
                 m2 = gcnt[NSEG * b + 2], m3 = gcnt[NSEG * b + 3];
  const bool segOVF = (m0 > LCAP) || (m1 > LCAP) || (m2 > LCAP) || (m3 > LCAP);
  const int n0 = m0 > LCAP ? LCAP : (int)m0;
  const int n1 = m1 > LCAP ? LCAP : (int)m1;
  const int n2 = m2 > LCAP ? LCAP : (int)m2;
  const int n3 = m3 > LCAP ? LCAP : (int)m3;
  const int off1 = n0, off2 = n0 + n1, off3 = n0 + n1 + n2;
  const int cntC = off3 + n3;
  const bool fast = !segOVF && (cntC <= WCAP);  // empirically always

  if (tid == 0) misc[3] = fast ? NMERGE : 0;  // walk overwrites when it runs
  gid[tid] = tid;

  // packed load: dst slot -> (segment, offset); zeros beyond cntC
  {
    const unsigned long long* gk = gkeys + (size_t)b * KTOT;
    for (int dst = tid; dst < WCAP; dst += 256) {
      unsigned long long v = 0ULL;
      if (fast && dst < cntC) {
        const int seg = (dst >= off1) + (dst >= off2) + (dst >= off3);
        const int base = (seg == 0) ? 0 : (seg == 1) ? off1 : (seg == 2) ? off2 : off3;
        v = gk[seg * LCAP + (dst - base)];
      }
      keys[dst] = v;
    }
  }
  __syncthreads();

  // ---- bitonic sort (descending) of 1024, 4 keys/thread (R4-proven shape) ----
  {
    const int e0 = 4 * tid;
    unsigned long long v0 = keys[e0], v1 = keys[e0 + 1],
                       v2 = keys[e0 + 2], v3 = keys[e0 + 3];
    for (int kk = 2; kk <= WCAP; kk <<= 1) {
      for (int jj = kk >> 1; jj > 0; jj >>= 1) {
        if (jj >= 256) {
          __syncthreads();
          keys[e0] = v0; keys[e0 + 1] = v1; keys[e0 + 2] = v2; keys[e0 + 3] = v3;
          __syncthreads();
          const int p0 = e0 ^ jj;
          unsigned long long o0 = keys[p0], o1 = keys[p0 + 1],
                             o2 = keys[p0 + 2], o3 = keys[p0 + 3];
          const bool km = ((e0 & kk) == 0) == ((e0 & jj) == 0);
          v0 = KEEP(v0, o0, km); v1 = KEEP(v1, o1, km);
          v2 = KEEP(v2, o2, km); v3 = KEEP(v3, o3, km);
        } else if (jj >= 4) {
          const int m = jj >> 2;
          unsigned long long o0 = shflx64(v0, m), o1 = shflx64(v1, m),
                             o2 = shflx64(v2, m), o3 = shflx64(v3, m);
          const bool km = ((e0 & kk) == 0) == ((e0 & jj) == 0);
          v0 = KEEP(v0, o0, km); v1 = KEEP(v1, o1, km);
          v2 = KEEP(v2, o2, km); v3 = KEEP(v3, o3, km);
        } else if (jj == 2) {
          const bool up = ((e0 & kk) == 0);
          CEX(v0, v2, up); CEX(v1, v3, up);
        } else {
          bool up0, up1;
          if (kk == 2) { up0 = true; up1 = false; }
          else { up0 = up1 = ((e0 & kk) == 0); }
          CEX(v0, v1, up0); CEX(v2, v3, up1);
        }
      }
    }
    __syncthreads();
    keys[e0] = v0; keys[e0 + 1] = v1; keys[e0 + 2] = v2; keys[e0 + 3] = v3;
  }
  __syncthreads();

  // ---- serial-shfl walk (wave 0), gid entirely in registers (R4-proven) ----
  if (fast && wid == 0) {
    int rg0 = lane, rg1 = 64 + lane, rg2 = 128 + lane, rg3 = 192 + lane;
    int done = 0;
    for (int cursor = 0; cursor < cntC && done < NMERGE; cursor += 64) {
      const int idx = cursor + lane;
      const unsigned long long key = (idx < cntC) ? keys[idx] : 0ULL;
      const int pi = 255 - (int)((key >> 8) & 255);
      const int pj = 255 - (int)(key & 255);
      const int sli = pi & 63, ssi = pi >> 6;
      const int slj = pj & 63, ssj = pj >> 6;
      const int a0 = __shfl(rg0, sli), a1 = __shfl(rg1, sli),
                a2 = __shfl(rg2, sli), a3 = __shfl(rg3, sli);
      const int b0 = __shfl(rg0, slj), b1 = __shfl(rg1, slj),
                b2 = __shfl(rg2, slj), b3 = __shfl(rg3, slj);
      int gpi = (ssi == 0) ? a0 : (ssi == 1) ? a1 : (ssi == 2) ? a2 : a3;
      int gpj = (ssj == 0) ? b0 : (ssj == 1) ? b1 : (ssj == 2) ? b2 : b3;
      if (key == 0ULL) { gpi = 0; gpj = 0; }
      for (;;) {
        const unsigned long long mask = __ballot(gpi != gpj);
        if (!mask) break;
        const int f = __ffsll((long long)mask) - 1;
        const int gi = __shfl(gpi, f), gj = __shfl(gpj, f);
        if (lane == f) gpi = gpj;
        if (gpi == gi) gpi = gj;
        if (gpj == gi) gpj = gj;
        if (rg0 == gi) rg0 = gj;
        if (rg1 == gi) rg1 = gj;
        if (rg2 == gi) rg2 = gj;
        if (rg3 == gi) rg3 = gj;
        if (++done == NMERGE) break;
      }
    }
    gid[lane] = rg0; gid[64 + lane] = rg1;
    gid[128 + lane] = rg2; gid[192 + lane] = rg3;
    if (lane == 0) misc[3] = done;
  }
  __syncthreads();

  // ---- exact fallback, CHEAP: rebuild knT in LDS, argmax from LDS ----
  {
    const int start = misc[3];
    if (start < NMERGE) {
      norm_tok(K, knT, b, tid);  // bit-identical to gm_gram's knT
      __syncthreads();
      for (int mg = start; mg < NMERGE; ++mg) {
        unsigned long long best = 0ULL;
        const int p = tid >> 1, q = tid & 1;
        const int jA = 128 + p, jB = 127 - p;
        const int lenA = jA;
        const int s0 = q * 128, s1 = (q == 1) ? 255 : 128;
        for (int e = s0; e < s1; ++e) {
          const int i = (e < lenA) ? e : (e - lenA);
          const int j = (e < lenA) ? jA : jB;
          if (gid[i] != gid[j]) {
            double s = 0.0;
            for (int d = 0; d < 64; ++d)
              s = fma((double)knT[d * NTOK + i], (double)knT[d * NTOK + j], s);
            const unsigned long long key =
                ((unsigned long long)mono_f32((float)s) << 16) |
                (unsigned)(65535 - ((i << 8) | j));
            if (key > best) best = key;
          }
        }
#pragma unroll
        for (int off = 32; off; off >>= 1) {
          unsigned long long o = __shfl_down(best, off);
          if (o > best) best = o;
        }
        if (lane == 0) red[wid] = best;
        __syncthreads();
        if (tid == 0) {
          unsigned long long mx = red[0];
          for (int w = 1; w < 4; ++w)
            if (red[w] > mx) mx = red[w];
          bkey[0] = mx;
        }
        __syncthreads();
        const unsigned long long bk = bkey[0];
        const int pi = 255 - (int)((bk >> 8) & 255);
        const int pj = 255 - (int)(bk & 255);
        const int gi = gid[pi], gj = gid[pj];
        __syncthreads();
        if (gid[tid] == gi) gid[tid] = gj;
        __syncthreads();
      }
    }
  }
  __syncthreads();
  // knT dead from here; accO (alias) becomes live.

  // ---- sizes + single-wave prefix scan + slots ----
  cnt256[tid] = 0;
  for (int e = tid; e < NOUT * DIM; e += 256) accO[e] = 0.0f;
  __syncthreads();
  atomicAdd(&cnt256[gid[tid]], 1);
  __syncthreads();
  if (wid == 0) {
    const int t4 = lane * 4;
    const int c0 = cnt256[t4 + 0] != 0, c1 = cnt256[t4 + 1] != 0,
              c2 = cnt256[t4 + 2] != 0, c3 = cnt256[t4 + 3] != 0;
    const int tot = c0 + c1 + c2 + c3;
    int run = tot;
#pragma unroll
    for (int off = 1; off < 64; off <<= 1) {
      int o = __shfl_up(run, off);
      if (lane >= off) run += o;
    }
    const int bs = run - tot;
    scn[t4 + 0] = bs + c0;
    scn[t4 + 1] = bs + c0 + c1;
    scn[t4 + 2] = bs + c0 + c1 + c2;
    scn[t4 + 3] = bs + tot;
  }
  __syncthreads();
  if (cnt256[tid]) rep[scn[tid] - 1] = tid;
  __syncthreads();

  // ---- accumulate V into slots (token tid) ----
  {
    const int slot = scn[gid[tid]] - 1;
    const float* vp = V + ((size_t)b * NTOK + tid) * DIM;
    float* dst = accO + slot * DIM;
#pragma unroll
    for (int q = 0; q < 16; ++q) {
      float4 v4 = *reinterpret_cast<const float4*>(vp + q * 4);
      atomicAdd(&dst[q * 4 + 0], v4.x);
      atomicAdd(&dst[q * 4 + 1], v4.y);
      atomicAdd(&dst[q * 4 + 2], v4.z);
      atomicAdd(&dst[q * 4 + 3], v4.w);
    }
  }
  __syncthreads();

  // ---- write outputs ----
  float* outMain = OUT + (size_t)b * (NOUT * DIM);
  for (int e = tid; e < NOUT * DIM; e += 256) {
    const int o = e >> 6;
    const float sz = (float)cnt256[rep[o]];
    outMain[e] = accO[e] / sz;
  }
  float* outSz = OUT + (size_t)NB * NOUT * DIM + (size_t)b * NOUT;
  if (tid < NOUT) outSz[tid] = (float)cnt256[rep[tid]];
}

// ============ fused fallback (R7, known-passing) — used only if ws too small ============
#define FPCAP 1024
#define FCAP 1024
#define SMEM_F 83584
__global__ __launch_bounds__(512) void gm_fused(const float* __restrict__ K,
                                                const float* __restrict__ V,
                                                float* __restrict__ OUT) {
  extern __shared__ char smem[];
  float* knT = (float*)smem;
  float* accO = (float*)smem;
  unsigned long long* keys = (unsigned long long*)(smem + 65536);
  unsigned* lpairs = (unsigned*)(smem + 73728);
  int* gid = (int*)(smem + 77824);
  int* cnt256 = (int*)(smem + 80896);
  int* scn = (int*)(smem + 81920);
  int* rep = (int*)(smem + 82944);
  unsigned long long* red = (unsigned long long*)(smem + 83456);
  unsigned long long* bkey = (unsigned long long*)(smem + 83520);
  int* misc = (int*)(smem + 83528);

  const int tid = threadIdx.x;
  const int lane = tid & 63;
  const int wid = tid >> 6;
  const int b = blockIdx.x;

  if (tid == 0) { misc[0] = 0; misc[1] = 0; }
  if (tid < NTOK) gid[tid] = tid;

  normalize_to_knT(K, knT, b, tid);
  __syncthreads();

  for (int t = tid; t < NTILES84; t += 512) {
    int ti, tj;
    tile84(t, ti, tj);
    const int i0 = ti * 8, j0 = tj * 4;
    float acc[8][4] = {};
#pragma unroll 4
    for (int d = 0; d < 64; ++d) {
      const float* row = knT + d * NTOK;
      const float4 a0 = *reinterpret_cast<const float4*>(row + i0);
      const float4 a1 = *reinterpret_cast<const float4*>(row + i0 + 4);
      const float4 bv = *reinterpret_cast<const float4*>(row + j0);
      const float aa[8] = {a0.x, a0.y, a0.z, a0.w, a1.x, a1.y, a1.z, a1.w};
      const float bb[4] = {bv.x, bv.y, bv.z, bv.w};
#pragma unroll
      for (int r = 0; r < 8; ++r)
#pragma unroll
        for (int c = 0; c < 4; ++c)
          acc[r][c] = fmaf(aa[r], bb[c], acc[r][c]);
    }
#pragma unroll
    for (int r = 0; r < 8; ++r)
#pragma unroll
      for (int c = 0; c < 4; ++c) {
        const int i = i0 + r, j = j0 + c;
        if (i < j && acc[r][c] >= SCREEN) {
          const int idx = atomicAdd(&misc[0], 1);
          if (idx < FPCAP) lpairs[idx] = (unsigned)((i << 8) | j);
        }
      }
  }
  __syncthreads();

  const int npRaw = misc[0];
  const int np = npRaw > FPCAP ? FPCAP : npRaw;
  const bool fullFB = (npRaw > FPCAP);
  for (int e = tid; e < np; e += 512) {
    const unsigned p = lpairs[e];
    const int i = (int)(p >> 8), j = (int)(p & 255u);
    double s = 0.0;
    for (int d = 0; d < 64; ++d)
      s = fma((double)knT[d * NTOK + i], (double)knT[d * NTOK + j], s);
    const float sf = (float)s;
    if (sf >= KAPPA) {
      const unsigned long long key =
          ((unsigned long long)mono_f32(sf) << 16) |
          (unsigned)(65535 - ((i << 8) | j));
      const int idx = atomicAdd(&misc[1], 1);
      keys[idx] = key;
    }
  }
  if (tid == 0) misc[3] = fullFB ? 0 : NMERGE;
  __syncthreads();
  const int nk = misc[1];

  {
    const int e0 = 2 * tid;
    unsigned long long v0 = (e0 + 0 < nk) ? keys[e0 + 0] : 0ULL;
    unsigned long long v1 = (e0 + 1 < nk) ? keys[e0 + 1] : 0ULL;
    for (int kk = 2; kk <= FCAP; kk <<= 1) {
      for (int jj = kk >> 1; jj > 0; jj >>= 1) {
        if (jj >= 128) {
          __syncthreads();
          keys[e0] = v0; keys[e0 + 1] = v1;
          __syncthreads();
          const int p0 = e0 ^ jj;
          const unsigned long long o0 = keys[p0], o1 = keys[p0 + 1];
          const bool km = ((e0 & kk) == 0) == ((e0 & jj) == 0);
          v0 = KEEP(v0, o0, km); v1 = KEEP(v1, o1, km);
        } else if (jj >= 2) {
          const int m = jj >> 1;
          const unsigned long long o0 = shflx64(v0, m), o1 = shflx64(v1, m);
          const bool km = ((e0 & kk) == 0) == ((e0 & jj) == 0);
          v0 = KEEP(v0, o0, km); v1 = KEEP(v1, o1, km);
        } else {
          const bool up = ((e0 & kk) == 0);
          CEX(v0, v1, up);
        }
      }
    }
    __syncthreads();
    keys[e0] = v0; keys[e0 + 1] = v1;
  }
  __syncthreads();

  if (misc[3] == NMERGE && wid == 0) {
    int rg0 = lane, rg1 = 64 + lane, rg2 = 128 + lane, rg3 = 192 + lane;
    int done = 0;
    for (int cursor = 0; cursor < nk && done < NMERGE; cursor += 64) {
      const int idx = cursor + lane;
      const unsigned long long key = (idx < nk) ? keys[idx] : 0ULL;
      const int pi = 255 - (int)((key >> 8) & 255);
      const int pj = 255 - (int)(key & 255);
      const int sli = pi & 63, ssi = pi >> 6;
      const int slj = pj & 63, ssj = pj >> 6;
      const int a0 = __shfl(rg0, sli), a1 = __shfl(rg1, sli),
                a2 = __shfl(rg2, sli), a3 = __shfl(rg3, sli);
      const int b0 = __shfl(rg0, slj), b1 = __shfl(rg1, slj),
                b2 = __shfl(rg2, slj), b3 = __shfl(rg3, slj);
      int gpi = (ssi == 0) ? a0 : (ssi == 1) ? a1 : (ssi == 2) ? a2 : a3;
      int gpj = (ssj == 0) ? b0 : (ssj == 1) ? b1 : (ssj == 2) ? b2 : b3;
      if (key == 0ULL) { gpi = 0; gpj = 0; }
      for (;;) {
        const unsigned long long mask = __ballot(gpi != gpj);
        if (!mask) break;
        const int f = __ffsll((long long)mask) - 1;
        const int gi = __shfl(gpi, f), gj = __shfl(gpj, f);
        if (lane == f) gpi = gpj;
        if (gpi == gi) gpi = gj;
        if (gpj == gi) gpj = gj;
        if (rg0 == gi) rg0 = gj;
        if (rg1 == gi) rg1 = gj;
        if (rg2 == gi) rg2 = gj;
        if (rg3 == gi) rg3 = gj;
        if (++done == NMERGE) break;
      }
    }
    gid[lane] = rg0; gid[64 + lane] = rg1;
    gid[128 + lane] = rg2; gid[192 + lane] = rg3;
    if (lane == 0) misc[3] = done;
  }
  __syncthreads();

  {
    const int start = misc[3];
    for (int mg = start; mg < NMERGE; ++mg) {
      unsigned long long best = 0ULL;
      const int p = tid >> 2, q = tid & 3;
      const int jA = 128 + p, jB = 127 - p;
      const int lenA = jA;
      const int s0 = q * 64, s1 = (q == 3) ? 255 : (q * 64 + 64);
      for (int e = s0; e < s1; ++e) {
        const int i = (e < lenA) ? e : (e - lenA);
        const int j = (e < lenA) ? jA : jB;
        if (gid[i] != gid[j]) {
          double s = 0.0;
          for (int d = 0; d < 64; ++d)
            s = fma((double)knT[d * NTOK + i], (double)knT[d * NTOK + j], s);
          const unsigned long long key =
              ((unsigned long long)mono_f32((float)s) << 16) |
              (unsigned)(65535 - ((i << 8) | j));
          if (key > best) best = key;
        }
      }
#pragma unroll
      for (int off = 32; off; off >>= 1) {
        unsigned long long o = __shfl_down(best, off);
        if (o > best) best = o;
      }
      if (lane == 0) red[wid] = best;
      __syncthreads();
      if (tid == 0) {
        unsigned long long mx = red[0];
        for (int w = 1; w < 8; ++w)
          if (red[w] > mx) mx = red[w];
        bkey[0] = mx;
      }
      __syncthreads();
      const unsigned long long bk = bkey[0];
      const int pi = 255 - (int)((bk >> 8) & 255);
      const int pj = 255 - (int)(bk & 255);
      const int gi = gid[pi], gj = gid[pj];
      __syncthreads();
      if (tid < NTOK && gid[tid] == gi) gid[tid] = gj;
      __syncthreads();
    }
  }
  __syncthreads();

  if (tid < NTOK) cnt256[tid] = 0;
  for (int e = tid; e < NOUT * DIM; e += 512) accO[e] = 0.0f;
  __syncthreads();
  if (tid < NTOK) atomicAdd(&cnt256[gid[tid]], 1);
  __syncthreads();
  if (wid == 0) {
    const int t4 = lane * 4;
    const int c0 = cnt256[t4 + 0] != 0, c1 = cnt256[t4 + 1] != 0,
              c2 = cnt256[t4 + 2] != 0, c3 = cnt256[t4 + 3] != 0;
    const int tot = c0 + c1 + c2 + c3;
    int run = tot;
#pragma unroll
    for (int off = 1; off < 64; off <<= 1) {
      int o = __shfl_up(run, off);
      if (lane >= off) run += o;
    }
    const int bs = run - tot;
    scn[t4 + 0] = bs + c0;
    scn[t4 + 1] = bs + c0 + c1;
    scn[t4 + 2] = bs + c0 + c1 + c2;
    scn[t4 + 3] = bs + tot;
  }
  __syncthreads();
  if (tid < NTOK && cnt256[tid]) rep[scn[tid] - 1] = tid;
  __syncthreads();

  {
    const int t = tid >> 1, h = tid & 1;
    const int slot = scn[gid[t]] - 1;
    const float* vp = V + ((size_t)b * NTOK + t) * DIM + h * 32;
    float* dst = accO + slot * DIM + h * 32;
#pragma unroll
    for (int q = 0; q < 8; ++q) {
      float4 v4 = *reinterpret_cast<const float4*>(vp + q * 4);
      atomicAdd(&dst[q * 4 + 0], v4.x);
      atomicAdd(&dst[q * 4 + 1], v4.y);
      atomicAdd(&dst[q * 4 + 2], v4.z);
      atomicAdd(&dst[q * 4 + 3], v4.w);
    }
  }
  __syncthreads();

  float* outMain = OUT + (size_t)b * (NOUT * DIM);
  for (int e = tid; e < NOUT * DIM; e += 512) {
    const int o = e >> 6;
    const float sz = (float)cnt256[rep[o]];
    outMain[e] = accO[e] / sz;
  }
  float* outSz = OUT + (size_t)NB * NOUT * DIM + (size_t)b * NOUT;
  for (int o = tid; o < NOUT; o += 512) outSz[o] = (float)cnt256[rep[o]];
}

extern "C" void kernel_launch(void* const* d_in, const int* in_sizes, int n_in,
                              void* d_out, int out_size, void* d_ws, size_t ws_size,
                              hipStream_t stream) {
  const float* K = (const float*)d_in[0];
  const float* V = (const float*)d_in[1];
  float* OUT = (float*)d_out;
  (void)in_sizes; (void)n_in; (void)out_size;

  // ws: gcnt[512] u32 @0 (2KB, padded to 4KB), gkeys @4096 (128*1536*8 = 1.5MB).
  // No memset needed: gm_gram writes every gcnt slot each call.
  const size_t need = 4096 + (size_t)NB * KTOT * sizeof(unsigned long long);
  if (ws_size >= need) {
    unsigned* gcnt = (unsigned*)d_ws;
    unsigned long long* gkeys = (unsigned long long*)((char*)d_ws + 4096);
    hipFuncSetAttribute(reinterpret_cast<const void*>(gm_gram),
                        hipFuncAttributeMaxDynamicSharedMemorySize, SMEM_A);
    hipFuncSetAttribute(reinterpret_cast<const void*>(gm_walk),
                        hipFuncAttributeMaxDynamicSharedMemorySize, SMEM_W);
    gm_gram<<<dim3(NB * 4), dim3(256), SMEM_A, stream>>>(K, gcnt, gkeys);
    gm_walk<<<dim3(NB), dim3(256), SMEM_W, stream>>>(K, V, OUT, gcnt, gkeys);
  } else {
    hipFuncSetAttribute(reinterpret_cast<const void*>(gm_fused),
                        hipFuncAttributeMaxDynamicSharedMemorySize, SMEM_F);
    gm_fused<<<dim3(NB), dim3(512), SMEM_F, stream>>>(K, V, OUT);
  }
}